// Round 8
// baseline (38.143 us; speedup 1.0000x reference)
//
#include <hip/hip_runtime.h>

#define VCNT 262144           // 64^3
#define NB 2
#define NT 128
#define HWPIX 65536           // 1*256*256
#define LOG2E 1.44269504088896340f

typedef float f32x2 __attribute__((ext_vector_type(2)));

static __device__ __forceinline__ float fast_exp2(float x) {
#if __has_builtin(__builtin_amdgcn_exp2f)
    return __builtin_amdgcn_exp2f(x);
#else
    float r; asm("v_exp_f32 %0, %1" : "=v"(r) : "v"(x)); return r;
#endif
}
static __device__ __forceinline__ float fast_rsq(float x) {
#if __has_builtin(__builtin_amdgcn_rsqf)
    return __builtin_amdgcn_rsqf(x);
#else
    float r; asm("v_rsq_f32 %0, %1" : "=v"(r) : "v"(x)); return r;
#endif
}

// ---------------------------------------------------------------------------
// Kernel 1: partial slice sums, needed slices only. 8 blocks/slice = 2048.
// (R6 version, verbatim — known-good config.)
// ---------------------------------------------------------------------------
__global__ __launch_bounds__(256) void slice_partial_kernel(
    const float* __restrict__ slices, const int* __restrict__ sidx,
    float* __restrict__ partials)
{
    const int s   = blockIdx.x >> 3;   // 0..255
    const int b   = s >> 7;
    const int tsl = s & 127;

    __shared__ int needed;
    if (threadIdx.x == 0) needed = 0;
    __syncthreads();
    if (threadIdx.x < NT && sidx[(b << 7) + threadIdx.x] == tsl) needed = 1;
    __syncthreads();
    if (!needed) return;               // uniform across block

    const int j = blockIdx.x & 7;
    const float4* p = (const float4*)(slices + (size_t)s * HWPIX) + j * 2048;

    float acc = 0.0f;
#pragma unroll
    for (int i = 0; i < 8; ++i) {
        float4 v = p[i * 256 + threadIdx.x];
        acc += (v.x + v.y) + (v.z + v.w);
    }
#pragma unroll
    for (int off = 32; off > 0; off >>= 1)
        acc += __shfl_down(acc, off, 64);

    __shared__ float ws[4];
    const int lane = threadIdx.x & 63;
    const int wid  = threadIdx.x >> 6;
    if (lane == 0) ws[wid] = acc;
    __syncthreads();
    if (threadIdx.x == 0)
        partials[blockIdx.x] = (ws[0] + ws[1]) + (ws[2] + ws[3]);
}

// ---------------------------------------------------------------------------
// Kernel 2: voxel reconstruction, transcendental-free inner loop.
//  Facts: grid coords are integers, centers are half-integers -> every
//  component |dx| in {0.5..63.5}, and d2 = dx^2+dy^2+dz^2 is EXACT in f32
//  (<= 12097, 16 bits) and >= 0.75.
//  w(d2) = exp(1/sqrt(d2)) from a log-spaced LDS lerp table for d2 in
//  [16, 16384): 10 octaves x 64 buckets (641 floats). Lerp err ~2e-6.
//  d2 < 16 (~0.1% of pairs) falls back to rsq+exp under a rare __any branch.
//  Dedup of duplicate slice indices as in R5/R6. 4 z-consecutive vox/thread.
// Grid: NB*VCNT/1024 = 512 blocks x 256 threads.
// ---------------------------------------------------------------------------
#define TBL_N 641

__global__ __launch_bounds__(256) void recon_kernel(
    const float* __restrict__ transforms,
    const int*   __restrict__ sidx,
    const float* __restrict__ partials,
    float*       __restrict__ out)
{
    __shared__ float4 ct[NT];   // x, y, z (raw), k*mean
    __shared__ float  kk[NT];   // k (multiplicity)
    __shared__ int    cnt[NT];
    __shared__ int    wcnt[2];
    __shared__ int    ncnt;
    __shared__ float  tbl[TBL_N];

    const int tid  = threadIdx.x;
    const int lane = tid & 63;
    const int wid  = tid >> 6;
    const int b    = blockIdx.x >> 8;                      // 256 blocks/batch
    const int v0   = ((blockIdx.x & 255) << 10) + (tid << 2);

    // ---- phase 1: zero multiplicity counters ----
    if (tid < NT) cnt[tid] = 0;
    __syncthreads();

    // ---- phase 2: multiplicity atomics + table build (independent) ----
    if (tid < NT) atomicAdd(&cnt[sidx[(b << 7) + tid]], 1);
#pragma unroll
    for (int i = tid; i < TBL_N; i += 256) {
        const int e = i >> 6, f = i & 63;
        const float d2v = __uint_as_float((unsigned)((131 + e) << 23) | (unsigned)(f << 17));
        tbl[i] = (float)exp(1.0 / sqrt((double)d2v));   // build in f64, exact
    }
    __syncthreads();

    // ---- phase 3: compact unique entries ----
    const int  k       = (tid < NT) ? cnt[tid] : 0;
    const bool neededf = (k > 0);
    const unsigned long long mask = __ballot(neededf);
    if (tid < NT && lane == 0) wcnt[wid] = (int)__popcll(mask);
    __syncthreads();
    if (neededf) {
        const int pos = (int)__popcll(mask & ((1ull << lane) - 1ull))
                      + (wid ? wcnt[0] : 0);
        const float* tr = transforms + (size_t)((b << 7) + tid) * 6;
        const float* pp = partials   + (size_t)((b << 7) + tid) * 8;
        float m = 0.0f;
#pragma unroll
        for (int i = 0; i < 8; ++i) m += pp[i];
        m *= (1.0f / (float)HWPIX);
        const float fk = (float)k;
        ct[pos] = make_float4(tr[0], tr[1], tr[2], fk * m);
        kk[pos] = fk;
    }
    if (tid == 0) ncnt = wcnt[0] + wcnt[1];
    __syncthreads();
    const int n = ncnt;

    // ---- main loop: 4 z-consecutive voxels/thread ----
    const float fx = (float)(v0 >> 12);
    const float fy = (float)((v0 >> 6) & 63);
    const float fz = (float)(v0 & 63);
    const f32x2 fzp = {fz, fz + 1.0f};

    f32x2 wsumA = {0.0f, 0.0f}, accA = {0.0f, 0.0f};   // z, z+1
    f32x2 wsumB = {0.0f, 0.0f}, accB = {0.0f, 0.0f};   // z+2, z+3

#pragma unroll 2
    for (int t = 0; t < n; ++t) {
        const float4 c  = ct[t];          // uniform addr -> LDS broadcast
        const float  kf = kk[t];
        const float dx = fx - c.x;
        const float dy = fy - c.y;
        const float base = fmaf(dy, dy, dx * dx);      // exact
        f32x2 dz0 = fzp - c.z;                          // (z, z+1)
        f32x2 dz1 = dz0 + 2.0f;                         // (z+2, z+3)
        f32x2 d2a, d2b;
        d2a.x = fmaf(dz0.x, dz0.x, base);  d2a.y = fmaf(dz0.y, dz0.y, base);
        d2b.x = fmaf(dz1.x, dz1.x, base);  d2b.y = fmaf(dz1.y, dz1.y, base);

        // table lookup + lerp (no transcendentals)
        float w0, w1, w2, w3;
        {
            const unsigned b0 = __float_as_uint(d2a.x);
            const unsigned b1 = __float_as_uint(d2a.y);
            const unsigned b2 = __float_as_uint(d2b.x);
            const unsigned b3 = __float_as_uint(d2b.y);
            int i0 = (int)(b0 >> 17) - 8384; i0 = i0 < 0 ? 0 : i0;
            int i1 = (int)(b1 >> 17) - 8384; i1 = i1 < 0 ? 0 : i1;
            int i2 = (int)(b2 >> 17) - 8384; i2 = i2 < 0 ? 0 : i2;
            int i3 = (int)(b3 >> 17) - 8384; i3 = i3 < 0 ? 0 : i3;
            const float f0 = (float)(b0 & 0x1FFFF) * (1.0f / 131072.0f);
            const float f1 = (float)(b1 & 0x1FFFF) * (1.0f / 131072.0f);
            const float f2 = (float)(b2 & 0x1FFFF) * (1.0f / 131072.0f);
            const float f3 = (float)(b3 & 0x1FFFF) * (1.0f / 131072.0f);
            const float a0 = tbl[i0], c0 = tbl[i0 + 1];   // ds_read2_b32
            const float a1 = tbl[i1], c1 = tbl[i1 + 1];
            const float a2 = tbl[i2], c2 = tbl[i2 + 1];
            const float a3 = tbl[i3], c3 = tbl[i3 + 1];
            w0 = fmaf(f0, c0 - a0, a0);
            w1 = fmaf(f1, c1 - a1, a1);
            w2 = fmaf(f2, c2 - a2, a2);
            w3 = fmaf(f3, c3 - a3, a3);
        }

        // rare near-field exact path (d2 < 16)
        const float mn = fminf(fminf(d2a.x, d2a.y), fminf(d2b.x, d2b.y));
        if (__any(mn < 16.0f)) {
            w0 = (d2a.x < 16.0f) ? fast_exp2(fast_rsq(d2a.x) * LOG2E) : w0;
            w1 = (d2a.y < 16.0f) ? fast_exp2(fast_rsq(d2a.y) * LOG2E) : w1;
            w2 = (d2b.x < 16.0f) ? fast_exp2(fast_rsq(d2b.x) * LOG2E) : w2;
            w3 = (d2b.y < 16.0f) ? fast_exp2(fast_rsq(d2b.y) * LOG2E) : w3;
        }

        wsumA.x = fmaf(w0, kf, wsumA.x);  wsumA.y = fmaf(w1, kf, wsumA.y);
        wsumB.x = fmaf(w2, kf, wsumB.x);  wsumB.y = fmaf(w3, kf, wsumB.y);
        accA.x  = fmaf(w0, c.w, accA.x);  accA.y  = fmaf(w1, c.w, accA.y);
        accB.x  = fmaf(w2, c.w, accB.x);  accB.y  = fmaf(w3, c.w, accB.y);
    }

    float4 o;
    o.x = accA.x / wsumA.x;
    o.y = accA.y / wsumA.y;
    o.z = accB.x / wsumB.x;
    o.w = accB.y / wsumB.y;
    *(float4*)(out + (size_t)b * VCNT + v0) = o;
}

// ---------------------------------------------------------------------------
extern "C" void kernel_launch(void* const* d_in, const int* in_sizes, int n_in,
                              void* d_out, int out_size, void* d_ws, size_t ws_size,
                              hipStream_t stream)
{
    const float* slices     = (const float*)d_in[0];  // (2,128,1,256,256) f32
    const float* transforms = (const float*)d_in[1];  // (2,128,6) f32
    const int*   sidx       = (const int*)d_in[2];    // (2,128) i32
    float* out      = (float*)d_out;                  // (2,1,64,64,64) f32
    float* partials = (float*)d_ws;                   // 2048 floats scratch

    slice_partial_kernel<<<NB * NT * 8, 256, 0, stream>>>(slices, sidx, partials);
    recon_kernel<<<NB * VCNT / 1024, 256, 0, stream>>>(transforms, sidx, partials, out);
}